// Round 8
// baseline (575.480 us; speedup 1.0000x reference)
//
#include <hip/hip_runtime.h>
#include <hip/hip_bf16.h>
#include <stdint.h>

// ---------- types ----------
typedef __attribute__((ext_vector_type(4))) float  f32x4;
typedef __attribute__((ext_vector_type(8))) short  bf16x8;
typedef __attribute__((ext_vector_type(8))) unsigned short u16x8;

#define MFMA16(d, x, y) d = __builtin_amdgcn_mfma_f32_16x16x32_bf16(x, y, d, 0, 0, 0)

// round f32 -> bf16 bits (RNE)
static __device__ inline unsigned short f2bf(float f) {
    union { float f; unsigned u; } a; a.f = f;
    unsigned u = a.u;
    unsigned lsb = (u >> 16) & 1u;
    u += 0x7fffu + lsb;
    return (unsigned short)(u >> 16);
}

// Emulate reference fp8_e4m3_round for positive x (x >= 1e-12).
static __device__ inline float fp8_e4m3_round(float x) {
    union { float f; unsigned u; } a; a.f = x;
    int e = (int)((a.u >> 23) & 255u) - 127;   // floor(log2(x)) exactly
    e = e < -6 ? -6 : (e > 8 ? 8 : e);
    union { unsigned u; float f; } stp, inv;
    stp.u = (unsigned)(e - 3 + 127) << 23;     // 2^(e-3)
    inv.u = (unsigned)(3 - e + 127) << 23;     // 2^(3-e)
    float r = rintf(x * inv.f) * stp.f;        // round-half-even == jnp.round
    return fminf(r, 448.0f);
}

// fp4 e2m1 level by strict midpoint comparison
static __device__ inline float fp4_level(float a) {
    return a > 2.5f ? (a > 3.5f ? (a > 5.0f ? 6.0f : 4.0f) : 3.0f)
                    : (a > 1.25f ? (a > 1.75f ? 2.0f : 1.5f)
                                 : (a > 0.75f ? 1.0f : (a > 0.25f ? 0.5f : 0.0f)));
}

// ---------- kernel 1: quantize+dequantize activations to bf16 ----------
__global__ void quant_x_kernel(const float* __restrict__ x, unsigned short* __restrict__ xd, int nblk) {
    int i = blockIdx.x * blockDim.x + threadIdx.x;
    if (i >= nblk) return;
    const float4* p = (const float4*)(x + (size_t)i * 16);
    float4 v0 = p[0], v1 = p[1], v2 = p[2], v3 = p[3];
    float vals[16] = { v0.x,v0.y,v0.z,v0.w, v1.x,v1.y,v1.z,v1.w,
                       v2.x,v2.y,v2.z,v2.w, v3.x,v3.y,v3.z,v3.w };
    float amax = 0.0f;
#pragma unroll
    for (int j = 0; j < 16; ++j) amax = fmaxf(amax, fabsf(vals[j]));
    float s0 = fmaxf(amax / 6.0f, 1e-12f);
    float s  = fmaxf(fp8_e4m3_round(s0), 1.0f / 512.0f);  // FP8_MIN = 2^-9
    u16x8 o0, o1;
#pragma unroll
    for (int j = 0; j < 16; ++j) {
        float v = vals[j] / s;
        float lev = fp4_level(fabsf(v));
        float q = copysignf(lev, v);
        unsigned short b = f2bf(q * s);
        if (j < 8) o0[j] = b; else o1[j - 8] = b;
    }
    u16x8* dst = (u16x8*)(xd + (size_t)i * 16);
    dst[0] = o0; dst[1] = o1;
}

// ---------- kernel 2: dequantize weights to bf16 ----------
__global__ void deq_w_kernel(const float* __restrict__ wq, const float* __restrict__ wsc,
                             unsigned short* __restrict__ wd, int nblk) {
    int i = blockIdx.x * blockDim.x + threadIdx.x;
    if (i >= nblk) return;
    float s = wsc[i];
    const float4* p = (const float4*)(wq + (size_t)i * 16);
    float4 v0 = p[0], v1 = p[1], v2 = p[2], v3 = p[3];
    float vals[16] = { v0.x,v0.y,v0.z,v0.w, v1.x,v1.y,v1.z,v1.w,
                       v2.x,v2.y,v2.z,v2.w, v3.x,v3.y,v3.z,v3.w };
    u16x8 o0, o1;
#pragma unroll
    for (int j = 0; j < 16; ++j) {
        unsigned short b = f2bf(vals[j] * s);
        if (j < 8) o0[j] = b; else o1[j - 8] = b;
    }
    u16x8* dst = (u16x8*)(wd + (size_t)i * 16);
    dst[0] = o0; dst[1] = o1;
}

// ---------- kernel 3: 256x256x64 bf16 GEMM, m201-faithful 4-phase schedule --
// C[M][N] = A[M][K] * B[N][K]^T + bias.  8 waves (2Mx4N), per-wave 128x64.
// LDS (128KB): A dbuf at 0/32768 (k-slice0 @+0, k-slice1 @+16384, st_16x32-
// swizzled 1024B subtiles); B same at 65536.
// 4 phases/K-tile, C-QUADRANT-major over full K=64, 16 MFMA per phase:
//  P1: read A-half0 (8) + B-half0 (4) [lgkm(8) hint]; bar; lgkm0; Q00; bar
//  P2: read B-half1 (4);                              bar; lgkm0; Q01; bar
//  P3: read A-half1 (8); stage B(t+2) k0,k1;          bar; lgkm0; Q11; bar
//  P4: stage A(t+2) k0,k1; vmcnt(8);                  bar;        Q10; bar
// ONE vmcnt per K-tile (P4, N=8 = newest P3+P4 stage loads kept; drains
// tile t+1's halves before P1(t+1) reads them, all waves barrier-gated).
// WAR: staging t+2 into t's buffer touches B region only after its last
// reads (P1/P2) drained at a preceding lgkm(0)+barrier; A region after
// P1/P3 reads likewise.  RAW for regs: compiler-counted lgkm + explicit
// lgkm(0)+sched_barrier(0) (rule 18) pin each 16-MFMA cluster.
// No compiler-tracked vmem in the loop (only gload_lds) -> manual vmcnt
// doesn't fight the compiler's waitcnt pass (round-6 lesson).
static __device__ __forceinline__ void stage_half(const unsigned short* g0, const unsigned short* g1,
                                                  size_t koff, char* d0) {
    __builtin_amdgcn_global_load_lds((const __attribute__((address_space(1))) void*)(g0 + koff),
                                     (__attribute__((address_space(3))) void*)d0, 16, 0, 0);
    __builtin_amdgcn_global_load_lds((const __attribute__((address_space(1))) void*)(g1 + koff),
                                     (__attribute__((address_space(3))) void*)(d0 + 1024), 16, 0, 0);
}

#define VM8    asm volatile("s_waitcnt vmcnt(8)" ::: "memory")
#define VM0    asm volatile("s_waitcnt vmcnt(0)" ::: "memory")
#define VMNONE (void)0

#define TILE(T, B, DOSTAGE, VMGATE) {                                   \
    const char* pA = lds + (B) * 32768 + wr * 8192 + lane_off;          \
    const char* pB = lds + 65536 + (B) * 32768 + wc * 4096 + lane_off;  \
    const size_t k2 = (size_t)((T) + 2) * 64;                           \
    /* ---- P1: A-half0 + B-half0 -> Q00 ---- */                        \
    _Pragma("unroll")                                                   \
    for (int m = 0; m < 4; ++m) {                                       \
        a0[2*m]   = *(const bf16x8*)(pA + m * 1024);                    \
        a0[2*m+1] = *(const bf16x8*)(pA + 16384 + m * 1024); }          \
    _Pragma("unroll")                                                   \
    for (int n = 0; n < 2; ++n) {                                       \
        b0[2*n]   = *(const bf16x8*)(pB + n * 1024);                    \
        b0[2*n+1] = *(const bf16x8*)(pB + 16384 + n * 1024); }          \
    asm volatile("s_waitcnt lgkmcnt(8)" ::: "memory");                  \
    __builtin_amdgcn_s_barrier();                                       \
    asm volatile("s_waitcnt lgkmcnt(0)" ::: "memory");                  \
    __builtin_amdgcn_sched_barrier(0);                                  \
    __builtin_amdgcn_s_setprio(1);                                      \
    _Pragma("unroll")                                                   \
    for (int m = 0; m < 4; ++m)                                         \
        _Pragma("unroll")                                               \
        for (int n = 0; n < 2; ++n) {                                   \
            MFMA16(acc[m][n], a0[2*m], b0[2*n]);                        \
            MFMA16(acc[m][n], a0[2*m+1], b0[2*n+1]); }                  \
    __builtin_amdgcn_s_setprio(0);                                      \
    __builtin_amdgcn_s_barrier();                                       \
    /* ---- P2: B-half1 -> Q01 ---- */                                  \
    _Pragma("unroll")                                                   \
    for (int n = 0; n < 2; ++n) {                                       \
        b1[2*n]   = *(const bf16x8*)(pB + (2 + n) * 1024);              \
        b1[2*n+1] = *(const bf16x8*)(pB + 16384 + (2 + n) * 1024); }    \
    __builtin_amdgcn_s_barrier();                                       \
    asm volatile("s_waitcnt lgkmcnt(0)" ::: "memory");                  \
    __builtin_amdgcn_sched_barrier(0);                                  \
    __builtin_amdgcn_s_setprio(1);                                      \
    _Pragma("unroll")                                                   \
    for (int m = 0; m < 4; ++m)                                         \
        _Pragma("unroll")                                               \
        for (int n = 0; n < 2; ++n) {                                   \
            MFMA16(acc[m][2 + n], a0[2*m], b1[2*n]);                    \
            MFMA16(acc[m][2 + n], a0[2*m+1], b1[2*n+1]); }              \
    __builtin_amdgcn_s_setprio(0);                                      \
    __builtin_amdgcn_s_barrier();                                       \
    /* ---- P3: A-half1; stage B(t+2) -> Q11 ---- */                    \
    _Pragma("unroll")                                                   \
    for (int m = 0; m < 4; ++m) {                                       \
        a1[2*m]   = *(const bf16x8*)(pA + (4 + m) * 1024);              \
        a1[2*m+1] = *(const bf16x8*)(pA + 16384 + (4 + m) * 1024); }    \
    if (DOSTAGE) {                                                      \
        stage_half(gB0, gB1, k2,      ldsB_w + (B) * 32768);            \
        stage_half(gB0, gB1, k2 + 32, ldsB_w + (B) * 32768 + 16384); }  \
    __builtin_amdgcn_s_barrier();                                       \
    asm volatile("s_waitcnt lgkmcnt(0)" ::: "memory");                  \
    __builtin_amdgcn_sched_barrier(0);                                  \
    __builtin_amdgcn_s_setprio(1);                                      \
    _Pragma("unroll")                                                   \
    for (int m = 0; m < 4; ++m)                                         \
        _Pragma("unroll")                                               \
        for (int n = 0; n < 2; ++n) {                                   \
            MFMA16(acc[4 + m][2 + n], a1[2*m], b1[2*n]);                \
            MFMA16(acc[4 + m][2 + n], a1[2*m+1], b1[2*n+1]); }          \
    __builtin_amdgcn_s_setprio(0);                                      \
    __builtin_amdgcn_s_barrier();                                       \
    /* ---- P4: stage A(t+2); vmcnt gate -> Q10 ---- */                 \
    if (DOSTAGE) {                                                      \
        stage_half(gA0, gA1, k2,      ldsA_w + (B) * 32768);            \
        stage_half(gA0, gA1, k2 + 32, ldsA_w + (B) * 32768 + 16384); }  \
    VMGATE;                                                             \
    __builtin_amdgcn_s_barrier();                                       \
    __builtin_amdgcn_s_setprio(1);                                      \
    _Pragma("unroll")                                                   \
    for (int m = 0; m < 4; ++m)                                         \
        _Pragma("unroll")                                               \
        for (int n = 0; n < 2; ++n) {                                   \
            MFMA16(acc[4 + m][n], a1[2*m], b0[2*n]);                    \
            MFMA16(acc[4 + m][n], a1[2*m+1], b0[2*n+1]); }              \
    __builtin_amdgcn_s_setprio(0);                                      \
    __builtin_amdgcn_s_barrier(); }

__global__ __launch_bounds__(512, 2)
void gemm_kernel(const unsigned short* __restrict__ A, const unsigned short* __restrict__ Bw,
                 const float* __restrict__ bias, float* __restrict__ C,
                 int M, int N, int K) {
    extern __shared__ char lds[];
    const int tid  = threadIdx.x;
    const int lane = tid & 63;
    const int wid  = tid >> 6;
    const int wr   = wid >> 2;       // 0..1
    const int wc   = wid & 3;        // 0..3

    const int NXB = N >> 8, NYB = M >> 8;
    int bid = blockIdx.x;
    int bx, by;
    if (NXB == 64 && NYB == 16) {    // XCD-aware swizzle (8 XCDs, 1024 wgs)
        int xcd = bid & 7, c = bid >> 3;
        bx = xcd * 8 + (c & 7);
        by = c >> 3;
    } else { bx = bid % NXB; by = bid / NXB; }

    const int NT = K >> 6;           // K-tiles of 64 (K=4096 -> 64, even)

    // read-side swizzled lane offset within a 1024B subtile (st_16x32, 1 bit)
    int w0 = (lane & 15) * 64 + ((lane >> 4) << 4);
    const int lane_off = w0 ^ (((w0 >> 9) & 1) << 5);
    // write-side inverse permutation for staging: lane -> (row, col)
    const int u   = (lane * 16) ^ (lane & 32);
    const int r_l = u >> 6;
    const int c_l = (u & 63) >> 1;

    const unsigned short* gA0 = A  + (size_t)(by * 256 + wid * 32 + r_l) * K + c_l;
    const unsigned short* gA1 = gA0 + (size_t)16 * K;
    const unsigned short* gB0 = Bw + (size_t)(bx * 256 + wid * 32 + r_l) * K + c_l;
    const unsigned short* gB1 = gB0 + (size_t)16 * K;
    char* ldsA_w = lds + wid * 2048 + lane * 16;           // + buf*32768 + s*16384
    char* ldsB_w = lds + 65536 + wid * 2048 + lane * 16;

    f32x4 acc[8][4];
#pragma unroll
    for (int m = 0; m < 8; ++m)
#pragma unroll
        for (int n = 0; n < 4; ++n)
#pragma unroll
            for (int j = 0; j < 4; ++j) acc[m][n][j] = 0.0f;

    bf16x8 a0[8], a1[8], b0[4], b1[4];

    // ---- prologue: stage tiles 0 and 1 fully (8 + 8 loads) ----
    stage_half(gA0, gA1, 0,   ldsA_w);
    stage_half(gA0, gA1, 32,  ldsA_w + 16384);
    stage_half(gB0, gB1, 0,   ldsB_w);
    stage_half(gB0, gB1, 32,  ldsB_w + 16384);
    stage_half(gA0, gA1, 64,  ldsA_w + 32768);
    stage_half(gA0, gA1, 96,  ldsA_w + 32768 + 16384);
    stage_half(gB0, gB1, 64,  ldsB_w + 32768);
    stage_half(gB0, gB1, 96,  ldsB_w + 32768 + 16384);
    asm volatile("s_waitcnt vmcnt(8)" ::: "memory");   // tile0 landed, tile1 in flight
    __builtin_amdgcn_s_barrier();

    // ---- main loop: tiles 0..NT-3 staged 2 ahead ----
    for (int t = 0; t <= NT - 4; t += 2) {
        TILE(t,     0, 1, VM8);
        TILE(t + 1, 1, 1, VM8);
    }
    // ---- tails: no staging; NT-2 drains everything for NT-1 ----
    TILE(NT - 2, 0, 0, VM0);
    TILE(NT - 1, 1, 0, VMNONE);

    // ---- C write: col = lane&15, row = (lane>>4)*4 + j ----
    const int row0 = by * 256 + wr * 128;
    const int col0 = bx * 256 + wc * 64;
#pragma unroll
    for (int nf = 0; nf < 4; ++nf) {
        int col = col0 + nf * 16 + (lane & 15);
        float bv = bias[col];
#pragma unroll
        for (int mf = 0; mf < 8; ++mf) {
#pragma unroll
            for (int j = 0; j < 4; ++j) {
                int row = row0 + mf * 16 + ((lane >> 4) << 2) + j;
                C[(size_t)row * N + col] = acc[mf][nf][j] + bv;
            }
        }
    }
}

// ---------- host ----------
extern "C" void kernel_launch(void* const* d_in, const int* in_sizes, int n_in,
                              void* d_out, int out_size, void* d_ws, size_t ws_size,
                              hipStream_t stream) {
    const float* x    = (const float*)d_in[0];
    const float* wq   = (const float*)d_in[1];
    const float* wsc  = (const float*)d_in[2];
    const float* bias = (const float*)d_in[3];
    float* out = (float*)d_out;

    const long N = in_sizes[3];                 // 16384
    const long K = (long)in_sizes[1] / N;       // 4096
    const long M = (long)in_sizes[0] / K;       // 4096

    size_t need = ((size_t)(M * K) + (size_t)(N * K)) * sizeof(unsigned short);
    if (ws_size < need) return;

    unsigned short* xd = (unsigned short*)d_ws;          // [M][K] bf16
    unsigned short* wd = xd + (size_t)M * K;             // [N][K] bf16

    {
        int nblk = (int)(M * K / 16);
        quant_x_kernel<<<(nblk + 255) / 256, 256, 0, stream>>>(x, xd, nblk);
    }
    {
        int nblk = (int)(N * K / 16);
        deq_w_kernel<<<(nblk + 255) / 256, 256, 0, stream>>>(wq, wsc, wd, nblk);
    }
    {
        hipFuncSetAttribute((const void*)gemm_kernel,
                            hipFuncAttributeMaxDynamicSharedMemorySize, 131072);
        int nwg = (int)((M / 256) * (N / 256));
        gemm_kernel<<<dim3(nwg), dim3(512), 131072, stream>>>(xd, wd, bias, out,
                                                              (int)M, (int)N, (int)K);
    }
}